// Round 7
// baseline (275.982 us; speedup 1.0000x reference)
//
#include <hip/hip_runtime.h>
#include <stdint.h>

// Problem constants
#define QP 127.0f
#define HW2 50176            // 224*224
#define NPIX 1605632         // 32*224*224
#define NELEM 25690112       // 32*16*224*224
#define ABS_GRID 2048        // k_absmax_wq grid (bmax sized for it)
#define NRG 56               // 224/4 row-groups per image
#define NBLK_CONV 1792       // 32 n * 56 row-groups

// ---- workspace layout (bytes) ----
#define WS_WQ    256         // 576 dwords packed weights (bytes 256..2560)
#define WS_SSUM  2560        // 16 x u64 (two's-complement i64) channel sums
#define WS_QSUM  2688        // 16 x double channel sum-of-squares
#define WS_BMAX  4096        // ABS_GRID floats of per-block |x| maxima (8 KB)
#define WS_XQ    (1 << 20)   // NPIX * 16B of cin-packed int8 activations
// hdr floats: hdr_f[1] = sw, hdr_f[2] = sx

typedef int v4i __attribute__((ext_vector_type(4)));

// ---- strip staging from xq: 6 full-width rows, coalesced (R4-verified) ----
__device__ __forceinline__ void stage_strip(const int4* __restrict__ xq,
                                            int4* sXs, int n, int r0, int tid) {
  #pragma unroll
  for (int j = 0; j < 6; ++j) {
    int g = r0 - 1 + j;
    if (tid < 224) {
      int4 v = {0, 0, 0, 0};
      if ((unsigned)g < 224u) v = xq[(n * 224 + g) * 224 + tid];
      sXs[j * 226 + 1 + tid] = v;
    } else if (tid < 226) {
      int4 z = {0, 0, 0, 0};
      sXs[j * 226 + ((tid == 224) ? 0 : 225)] = z;   // left / right pad col
    }
  }
}

// ---- MFMA conv geometry (R6-verified) ----
// Implicit GEMM per strip: M = 896 px, N = 16 cout, K = 144 zero-padded to 192.
// A (lane row = lane&15 = px-in-tile, chunk = lane>>4): cin-packed xq int4 of
// pixel (y+kh-1, x0+row+kw-1) for tap 4m+chunk. B: wq4[cout*9+tap], cout=lane&15;
// taps 9..11 ZERO (nullifies clamped A reads). D: cout=lane&15, px=(lane>>4)*4+reg.
__device__ __forceinline__ void conv_lane_setup(const int4* __restrict__ wq4,
                                                int ccol, int chunk,
                                                v4i (&bfrag)[3], int (&abase)[3]) {
  #pragma unroll
  for (int m = 0; m < 3; ++m) {
    int tap = 4 * m + chunk;
    v4i bv = {0, 0, 0, 0};
    if (tap <= 8) {
      int4 t = wq4[ccol * 9 + tap];
      bv[0] = t.x; bv[1] = t.y; bv[2] = t.z; bv[3] = t.w;
    }
    bfrag[m] = bv;
    int tc = (tap > 8) ? 8 : tap;                    // clamp: B=0 kills it
    int kh = tc / 3, kw = tc - kh * 3;
    abase[m] = kh * 226 + ccol + kw;                 // add ty*226 + x0 at use
  }
}

// ---------------- D1: absmax(x) + weight quant + zero stat accumulators ----------------
__global__ __launch_bounds__(256) void k_absmax_wq(const float* __restrict__ x,
                                                   const float* __restrict__ w,
                                                   char* __restrict__ ws) {
  __shared__ float red[4];
  __shared__ float s_sw;
  float* hdr_f = (float*)ws;
  float* bmax = (float*)(ws + WS_BMAX);
  int* wq = (int*)(ws + WS_WQ);
  const int tid = threadIdx.x;

  if (blockIdx.x == 0 && tid < 16) {                 // zero stats (read 2 kernels later)
    ((unsigned long long*)(ws + WS_SSUM))[tid] = 0ull;
    ((double*)(ws + WS_QSUM))[tid] = 0.0;
  }

  const float4* x4 = (const float4*)x;
  float m = 0.0f;
  for (int i = blockIdx.x * 256 + tid; i < NELEM / 4; i += ABS_GRID * 256) {
    float4 v = x4[i];
    m = fmaxf(m, fmaxf(fmaxf(fabsf(v.x), fabsf(v.y)),
                       fmaxf(fabsf(v.z), fabsf(v.w))));
  }
  #pragma unroll
  for (int off = 32; off; off >>= 1) m = fmaxf(m, __shfl_down(m, off, 64));
  if ((tid & 63) == 0) red[tid >> 6] = m;
  __syncthreads();
  if (tid == 0)
    bmax[blockIdx.x] = fmaxf(fmaxf(red[0], red[1]), fmaxf(red[2], red[3]));

  if (blockIdx.x == 0) {                             // weight quant (verified)
    __syncthreads();                                 // red[] reuse
    float mw = 0.0f;
    for (int i = tid; i < 2304; i += 256) mw = fmaxf(mw, fabsf(w[i]));
    #pragma unroll
    for (int off = 32; off; off >>= 1) mw = fmaxf(mw, __shfl_down(mw, off, 64));
    if ((tid & 63) == 0) red[tid >> 6] = mw;
    __syncthreads();
    if (tid == 0) {
      float sw = fmaxf(fmaxf(red[0], red[1]), fmaxf(red[2], red[3])) / QP;
      hdr_f[1] = sw;
      s_sw = sw;
    }
    __syncthreads();
    float sw = s_sw;
    // pack: wq[(cout*9 + kh*3+kw)*4 + c4], byte j of dword = cin 4*c4+j
    for (int i = tid; i < 576; i += 256) {
      int cout = i / 36; int r = i - cout * 36;
      int tap = r >> 2;  int c4 = r & 3;
      int kh = tap / 3, kw = tap - kh * 3;
      unsigned bits = 0;
      #pragma unroll
      for (int j = 0; j < 4; ++j) {
        int cin = c4 * 4 + j;
        float v = w[((cout * 16 + cin) * 3 + kh) * 3 + kw];
        int q = (int)rintf(v / sw);                  // rint = round-half-even
        q = max(-127, min(127, q));
        bits |= ((unsigned)(q & 0xff)) << (8 * j);
      }
      wq[i] = (int)bits;
    }
  }
}

// ---------------- D2: fused quantize-on-stage + MFMA conv + atomic stats ----------------
// Quantize path = R5-mega-verified (336 tasks, float4 16-ch pack, interior rows
// -> xq). Conv+stats = R6-verified MFMA core; per-block channel sums go to
// global via one u64 atomic (EXACT integer sum) + one f64 atomic (sum of sq).
__global__ __launch_bounds__(256) void k_quant_stats(const float* __restrict__ x,
                                                     char* __restrict__ ws) {
  __shared__ int4 sXs[6 * 226];                      // 21696 B
  __shared__ int   sS[4][16];
  __shared__ float sQ[4][16];
  __shared__ float sRed4[4];
  const float* __restrict__ bmax = (const float*)(ws + WS_BMAX);
  const int4* __restrict__ wq4 = (const int4*)(ws + WS_WQ);
  float* hdr_f = (float*)ws;
  int4* xq = (int4*)(ws + WS_XQ);
  const int tid = threadIdx.x;

  // ---- reduce bmax -> sx (verified pattern) ----
  float m = 0.0f;
  for (int i = tid; i < ABS_GRID; i += 256) m = fmaxf(m, bmax[i]);
  #pragma unroll
  for (int off = 32; off; off >>= 1) m = fmaxf(m, __shfl_down(m, off, 64));
  if ((tid & 63) == 0) sRed4[tid >> 6] = m;
  __syncthreads();
  const float sx =
      fmaxf(fmaxf(sRed4[0], sRed4[1]), fmaxf(sRed4[2], sRed4[3])) / QP;
  if (blockIdx.x == 0 && tid == 0) hdr_f[2] = sx;    // for k_conv_out finalize

  const int b = blockIdx.x;
  const int n = b / NRG, rg = b - n * NRG;
  const int r0 = rg * 4;

  // ---- quantize-stage: task = (row j of 6, group g of 56), 4 px each ----
  for (int task = tid; task < 336; task += 256) {
    int j = task / 56, g = task - j * 56;
    int gr = r0 - 1 + j;
    int4 v[4] = {{0,0,0,0}, {0,0,0,0}, {0,0,0,0}, {0,0,0,0}};
    if ((unsigned)gr < 224u) {
      const float4* xb = (const float4*)x + (size_t)n * 16 * (HW2 / 4)
                         + gr * 56 + g;
      unsigned comp[4][4];
      #pragma unroll
      for (int k = 0; k < 4; ++k)
        #pragma unroll
        for (int q4 = 0; q4 < 4; ++q4) comp[k][q4] = 0u;
      #pragma unroll
      for (int c = 0; c < 16; ++c) {
        float4 vc = xb[c * (HW2 / 4)];
        float f[4] = {vc.x, vc.y, vc.z, vc.w};
        #pragma unroll
        for (int k = 0; k < 4; ++k) {
          int q = (int)rintf(f[k] / sx);             // f32 div, matches ref
          q = max(-127, min(127, q));
          comp[k][c >> 2] |= ((unsigned)(q & 0xff)) << (8 * (c & 3));
        }
      }
      #pragma unroll
      for (int k = 0; k < 4; ++k) {
        v[k].x = (int)comp[k][0]; v[k].y = (int)comp[k][1];
        v[k].z = (int)comp[k][2]; v[k].w = (int)comp[k][3];
      }
      if (j >= 1 && j <= 4) {                        // interior row: owned here
        #pragma unroll
        for (int k = 0; k < 4; ++k)
          xq[(n * 224 + gr) * 224 + 4 * g + k] = v[k];
      }
    }
    #pragma unroll
    for (int k = 0; k < 4; ++k) sXs[j * 226 + 1 + 4 * g + k] = v[k];
  }
  if (tid >= 244) {                                  // 12 pad entries (6 rows x 2)
    int idx = tid - 244;
    int4 z = {0, 0, 0, 0};
    sXs[(idx >> 1) * 226 + ((idx & 1) ? 225 : 0)] = z;
  }

  const int lane = tid & 63, wid = tid >> 6;
  const int ccol = lane & 15, chunk = lane >> 4;
  v4i bfrag[3];
  int abase[3];
  conv_lane_setup(wq4, ccol, chunk, bfrag, abase);
  __syncthreads();

  // ---- MFMA conv + in-register stats (R6-verified) ----
  int   sAcc = 0;                                    // exact int row-sums
  float qAcc = 0.0f;                                 // f32 sum of squares
  for (int t = wid; t < 56; t += 4) {                // 14 tiles per wave
    int ty = t / 14, x0 = (t - ty * 14) << 4;
    int off = ty * 226 + x0;
    v4i acc = {0, 0, 0, 0};
    #pragma unroll
    for (int m3 = 0; m3 < 3; ++m3) {
      int4 av = sXs[off + abase[m3]];
      v4i a; a[0] = av.x; a[1] = av.y; a[2] = av.z; a[3] = av.w;
      acc = __builtin_amdgcn_mfma_i32_16x16x64_i8(a, bfrag[m3], acc, 0, 0, 0);
    }
    #pragma unroll
    for (int r = 0; r < 4; ++r) {
      int d = acc[r];                                // exact conv integer
      sAcc += d;
      float f = (float)d;
      qAcc += f * f;
    }
  }
  sAcc += __shfl_xor(sAcc, 16, 64);
  sAcc += __shfl_xor(sAcc, 32, 64);
  qAcc += __shfl_xor(qAcc, 16, 64);
  qAcc += __shfl_xor(qAcc, 32, 64);
  if (lane < 16) { sS[wid][ccol] = sAcc; sQ[wid][ccol] = qAcc; }
  __syncthreads();
  if (tid < 16) {
    int c = tid;
    long long s4 = (long long)sS[0][c] + sS[1][c] + sS[2][c] + sS[3][c];
    atomicAdd(((unsigned long long*)(ws + WS_SSUM)) + c,
              (unsigned long long)s4);               // two's-complement exact
  } else if (tid < 32) {
    int c = tid & 15;
    float q4 = sQ[0][c] + sQ[1][c] + sQ[2][c] + sQ[3][c];
    atomicAdd(((double*)(ws + WS_QSUM)) + c, (double)q4);
  }
}

// ---------------- D3: inline finalize + MFMA strip conv, output pass ----------------
__global__ __launch_bounds__(256) void k_conv_out(const char* __restrict__ ws,
                                                  const float* __restrict__ gamma,
                                                  const float* __restrict__ beta,
                                                  float* __restrict__ out) {
  __shared__ int4 sXs[6 * 226];
  __shared__ float sAB[32];                          // A[16], B[16]
  const int4* __restrict__ xq = (const int4*)(ws + WS_XQ);
  const int4* __restrict__ wq4 = (const int4*)(ws + WS_WQ);
  const float* hdr_f = (const float*)ws;

  const int tid = threadIdx.x;
  const int b = blockIdx.x;
  const int n = b / NRG, rg = b - n * NRG;
  const int r0 = rg * 4;

  stage_strip(xq, sXs, n, r0, tid);

  // ---- finalize (verified double formula; 32 scalars, all blocks identical) ----
  if (tid < 16) {
    unsigned long long us = ((const unsigned long long*)(ws + WS_SSUM))[tid];
    double S = (double)(long long)us;                // exact integer sum
    double Q = ((const double*)(ws + WS_QSUM))[tid];
    float sf = hdr_f[2] * hdr_f[1];                  // sx * sw (f32, verified)
    double s = (double)sf;
    const double M = (double)NPIX;
    double mean = s * S / M;
    double ey2 = s * s * Q / M;
    double var = ey2 - mean * mean;                  // biased var, matches jnp.var
    double inv = (double)gamma[tid] / sqrt(var + 1e-5);
    sAB[tid] = (float)(s * inv);                     // A: applied to raw int acc
    sAB[16 + tid] = (float)((double)beta[tid] - mean * inv);  // B
  }

  const int lane = tid & 63, wid = tid >> 6;
  const int ccol = lane & 15, chunk = lane >> 4;
  v4i bfrag[3];
  int abase[3];
  conv_lane_setup(wq4, ccol, chunk, bfrag, abase);
  __syncthreads();

  const float Af = sAB[ccol];                        // BN scale for this cout
  const float Bf = sAB[16 + ccol];                   // BN shift

  float* oplane = out + ((size_t)n * 16 + ccol) * HW2;
  for (int t = wid; t < 56; t += 4) {
    int ty = t / 14, x0 = (t - ty * 14) << 4;
    int off = ty * 226 + x0;
    v4i acc = {0, 0, 0, 0};
    #pragma unroll
    for (int m3 = 0; m3 < 3; ++m3) {
      int4 av = sXs[off + abase[m3]];
      v4i a; a[0] = av.x; a[1] = av.y; a[2] = av.z; a[3] = av.w;
      acc = __builtin_amdgcn_mfma_i32_16x16x64_i8(a, bfrag[m3], acc, 0, 0, 0);
    }
    // D: px = chunk*4 + r (cols x0+chunk*4 .. +3 of output row r0+ty)
    float4 o;
    o.x = fminf(fmaxf(fmaf((float)acc[0], Af, Bf), 0.0f), 6.0f);
    o.y = fminf(fmaxf(fmaf((float)acc[1], Af, Bf), 0.0f), 6.0f);
    o.z = fminf(fmaxf(fmaf((float)acc[2], Af, Bf), 0.0f), 6.0f);
    o.w = fminf(fmaxf(fmaf((float)acc[3], Af, Bf), 0.0f), 6.0f);
    int y = r0 + ty, xb = x0 + chunk * 4;            // xb % 4 == 0: aligned
    *(float4*)&oplane[y * 224 + xb] = o;
  }
}

extern "C" void kernel_launch(void* const* d_in, const int* in_sizes, int n_in,
                              void* d_out, int out_size, void* d_ws, size_t ws_size,
                              hipStream_t stream) {
  const float* x = (const float*)d_in[0];
  const float* w = (const float*)d_in[1];
  const float* gamma = (const float*)d_in[2];
  const float* beta = (const float*)d_in[3];
  float* out = (float*)d_out;
  char* ws = (char*)d_ws;

  k_absmax_wq<<<ABS_GRID, 256, 0, stream>>>(x, w, ws);
  k_quant_stats<<<NBLK_CONV, 256, 0, stream>>>(x, ws);
  k_conv_out<<<NBLK_CONV, 256, 0, stream>>>(ws, gamma, beta, out);
}

// Round 8
// 249.441 us; speedup vs baseline: 1.1064x; 1.1064x over previous
//
#include <hip/hip_runtime.h>
#include <stdint.h>

// Problem constants
#define QP 127.0f
#define HW2 50176            // 224*224
#define NPIX 1605632         // 32*224*224
#define NELEM 25690112       // 32*16*224*224
#define ABS_GRID 2048        // k_absmax_wq grid (bmax sized for it)
#define NRG8 28              // 224/8 row-groups per image
#define NBLK_CONV 896        // 32 n * 28 row-groups (8 rows per block)

// ---- workspace layout (bytes) ----
#define WS_WQ    256         // 576 dwords packed weights (bytes 256..2560)
#define WS_SSUM  2560        // 16 x u64 (two's-complement i64) channel sums
#define WS_QSUM  2688        // 16 x double channel sum-of-squares
#define WS_BMAX  4096        // ABS_GRID floats of per-block |x| maxima (8 KB)
#define WS_XQ    (1 << 20)   // NPIX * 16B of cin-packed int8 activations
// hdr floats: hdr_f[1] = sw, hdr_f[2] = sx

typedef int v4i __attribute__((ext_vector_type(4)));

// ---- strip staging from xq: 10 full-width rows (8 out + 2 halo), coalesced ----
// (R4-verified pattern, extended 6->10 rows.)
__device__ __forceinline__ void stage_strip10(const int4* __restrict__ xq,
                                              int4* sXs, int n, int r0, int tid) {
  #pragma unroll
  for (int j = 0; j < 10; ++j) {
    int g = r0 - 1 + j;
    if (tid < 224) {
      int4 v = {0, 0, 0, 0};
      if ((unsigned)g < 224u) v = xq[(n * 224 + g) * 224 + tid];
      sXs[j * 226 + 1 + tid] = v;
    } else if (tid < 226) {
      int4 z = {0, 0, 0, 0};
      sXs[j * 226 + ((tid == 224) ? 0 : 225)] = z;   // left / right pad col
    }
  }
}

// ---- MFMA conv geometry (R6-verified) ----
// Implicit GEMM: M = px tiles of 16, N = 16 cout, K = 144 zero-padded to 192.
// A (lane row = lane&15 = px-in-tile, chunk = lane>>4): cin-packed xq int4 of
// pixel (y+kh-1, x0+row+kw-1) for tap 4m+chunk. B: wq4[cout*9+tap], cout=lane&15;
// taps 9..11 ZERO (nullifies clamped A reads). D: cout=lane&15, px=(lane>>4)*4+reg.
__device__ __forceinline__ void conv_lane_setup(const int4* __restrict__ wq4,
                                                int ccol, int chunk,
                                                v4i (&bfrag)[3], int (&abase)[3]) {
  #pragma unroll
  for (int m = 0; m < 3; ++m) {
    int tap = 4 * m + chunk;
    v4i bv = {0, 0, 0, 0};
    if (tap <= 8) {
      int4 t = wq4[ccol * 9 + tap];
      bv[0] = t.x; bv[1] = t.y; bv[2] = t.z; bv[3] = t.w;
    }
    bfrag[m] = bv;
    int tc = (tap > 8) ? 8 : tap;                    // clamp: B=0 kills it
    int kh = tc / 3, kw = tc - kh * 3;
    abase[m] = kh * 226 + ccol + kw;                 // add ty*226 + x0 at use
  }
}

// ---------------- D1: absmax(x) + weight quant + zero stat accumulators ----------------
// (R7-verified.)
__global__ __launch_bounds__(256) void k_absmax_wq(const float* __restrict__ x,
                                                   const float* __restrict__ w,
                                                   char* __restrict__ ws) {
  __shared__ float red[4];
  __shared__ float s_sw;
  float* hdr_f = (float*)ws;
  float* bmax = (float*)(ws + WS_BMAX);
  int* wq = (int*)(ws + WS_WQ);
  const int tid = threadIdx.x;

  if (blockIdx.x == 0 && tid < 16) {                 // zero stats (read 2 kernels later)
    ((unsigned long long*)(ws + WS_SSUM))[tid] = 0ull;
    ((double*)(ws + WS_QSUM))[tid] = 0.0;
  }

  const float4* x4 = (const float4*)x;
  float m = 0.0f;
  for (int i = blockIdx.x * 256 + tid; i < NELEM / 4; i += ABS_GRID * 256) {
    float4 v = x4[i];
    m = fmaxf(m, fmaxf(fmaxf(fabsf(v.x), fabsf(v.y)),
                       fmaxf(fabsf(v.z), fabsf(v.w))));
  }
  #pragma unroll
  for (int off = 32; off; off >>= 1) m = fmaxf(m, __shfl_down(m, off, 64));
  if ((tid & 63) == 0) red[tid >> 6] = m;
  __syncthreads();
  if (tid == 0)
    bmax[blockIdx.x] = fmaxf(fmaxf(red[0], red[1]), fmaxf(red[2], red[3]));

  if (blockIdx.x == 0) {                             // weight quant (verified)
    __syncthreads();                                 // red[] reuse
    float mw = 0.0f;
    for (int i = tid; i < 2304; i += 256) mw = fmaxf(mw, fabsf(w[i]));
    #pragma unroll
    for (int off = 32; off; off >>= 1) mw = fmaxf(mw, __shfl_down(mw, off, 64));
    if ((tid & 63) == 0) red[tid >> 6] = mw;
    __syncthreads();
    if (tid == 0) {
      float sw = fmaxf(fmaxf(red[0], red[1]), fmaxf(red[2], red[3])) / QP;
      hdr_f[1] = sw;
      s_sw = sw;
    }
    __syncthreads();
    float sw = s_sw;
    // pack: wq[(cout*9 + kh*3+kw)*4 + c4], byte j of dword = cin 4*c4+j
    for (int i = tid; i < 576; i += 256) {
      int cout = i / 36; int r = i - cout * 36;
      int tap = r >> 2;  int c4 = r & 3;
      int kh = tap / 3, kw = tap - kh * 3;
      unsigned bits = 0;
      #pragma unroll
      for (int j = 0; j < 4; ++j) {
        int cin = c4 * 4 + j;
        float v = w[((cout * 16 + cin) * 3 + kh) * 3 + kw];
        int q = (int)rintf(v / sw);                  // rint = round-half-even
        q = max(-127, min(127, q));
        bits |= ((unsigned)(q & 0xff)) << (8 * j);
      }
      wq[i] = (int)bits;
    }
  }
}

// ---------------- D2: quantize x -> NHWC cin-packed int8 (streaming) ----------------
// (R6-verified verbatim: balanced 1x work, coalesced, no redundancy.)
__global__ __launch_bounds__(256) void k_quant_x(const float* __restrict__ x,
                                                 char* __restrict__ ws) {
  __shared__ float sRed4[4];
  const float* __restrict__ bmax = (const float*)(ws + WS_BMAX);
  float* hdr_f = (float*)ws;
  int4* xq = (int4*)(ws + WS_XQ);
  const int tid = threadIdx.x;

  float m = 0.0f;
  for (int i = tid; i < ABS_GRID; i += 256) m = fmaxf(m, bmax[i]);
  #pragma unroll
  for (int off = 32; off; off >>= 1) m = fmaxf(m, __shfl_down(m, off, 64));
  if ((tid & 63) == 0) sRed4[tid >> 6] = m;
  __syncthreads();
  const float sx =
      fmaxf(fmaxf(sRed4[0], sRed4[1]), fmaxf(sRed4[2], sRed4[3])) / QP;
  if (blockIdx.x == 0 && tid == 0) hdr_f[2] = sx;    // for k_conv_out finalize

  int t = blockIdx.x * 256 + tid;                    // grid 1568*256 = NPIX/4
  int p0 = t * 4;
  int n = p0 / HW2;                                  // HW2 % 4 == 0: no n-crossing
  int hw = p0 - n * HW2;
  const float4* xb = (const float4*)(x + (size_t)n * 16 * HW2 + hw);
  unsigned comp[4][4];
  #pragma unroll
  for (int j = 0; j < 4; ++j)
    #pragma unroll
    for (int k = 0; k < 4; ++k) comp[j][k] = 0u;
  #pragma unroll
  for (int c = 0; c < 16; ++c) {
    float4 vc = xb[c * (HW2 / 4)];
    float f[4] = {vc.x, vc.y, vc.z, vc.w};
    #pragma unroll
    for (int j = 0; j < 4; ++j) {
      int q = (int)rintf(f[j] / sx);                 // f32 div, matches ref
      q = max(-127, min(127, q));
      comp[j][c >> 2] |= ((unsigned)(q & 0xff)) << (8 * (c & 3));
    }
  }
  #pragma unroll
  for (int j = 0; j < 4; ++j) {
    int4 v;
    v.x = (int)comp[j][0]; v.y = (int)comp[j][1];
    v.z = (int)comp[j][2]; v.w = (int)comp[j][3];
    xq[p0 + j] = v;
  }
}

// ---------------- D3: MFMA conv (8 rows/block) + atomic stats ----------------
// Conv core = R6-verified; stats path = R7-verified (u64 exact int + f64 sq).
__global__ __launch_bounds__(256) void k_conv_stats(const char* __restrict__ ws_c,
                                                    char* __restrict__ ws) {
  __shared__ int4 sXs[10 * 226];                     // 36160 B
  __shared__ int   sS[4][16];
  __shared__ float sQ[4][16];
  const int4* __restrict__ xq = (const int4*)(ws_c + WS_XQ);
  const int4* __restrict__ wq4 = (const int4*)(ws_c + WS_WQ);

  const int tid = threadIdx.x;
  const int b = blockIdx.x;
  const int n = b / NRG8, rg = b - n * NRG8;
  const int r0 = rg * 8;

  stage_strip10(xq, sXs, n, r0, tid);

  const int lane = tid & 63, wid = tid >> 6;
  const int ccol = lane & 15, chunk = lane >> 4;
  v4i bfrag[3];
  int abase[3];
  conv_lane_setup(wq4, ccol, chunk, bfrag, abase);
  __syncthreads();

  int   sAcc = 0;                                    // exact int row-sums
  float qAcc = 0.0f;                                 // f32 sum of squares
  for (int t = wid; t < 112; t += 4) {               // 28 tiles per wave
    int ty = t / 14, x0 = (t - ty * 14) << 4;
    int off = ty * 226 + x0;
    v4i acc = {0, 0, 0, 0};
    #pragma unroll
    for (int m3 = 0; m3 < 3; ++m3) {
      int4 av = sXs[off + abase[m3]];
      v4i a; a[0] = av.x; a[1] = av.y; a[2] = av.z; a[3] = av.w;
      acc = __builtin_amdgcn_mfma_i32_16x16x64_i8(a, bfrag[m3], acc, 0, 0, 0);
    }
    #pragma unroll
    for (int r = 0; r < 4; ++r) {
      int d = acc[r];                                // exact conv integer
      sAcc += d;                                     // |sum| <= 112*2.33M < 2^31
      float f = (float)d;
      qAcc += f * f;
    }
  }
  sAcc += __shfl_xor(sAcc, 16, 64);
  sAcc += __shfl_xor(sAcc, 32, 64);
  qAcc += __shfl_xor(qAcc, 16, 64);
  qAcc += __shfl_xor(qAcc, 32, 64);
  if (lane < 16) { sS[wid][ccol] = sAcc; sQ[wid][ccol] = qAcc; }
  __syncthreads();
  if (tid < 16) {
    int c = tid;
    long long s4 = (long long)sS[0][c] + sS[1][c] + sS[2][c] + sS[3][c];
    atomicAdd(((unsigned long long*)(ws + WS_SSUM)) + c,
              (unsigned long long)s4);               // two's-complement exact
  } else if (tid < 32) {
    int c = tid & 15;
    float q4 = sQ[0][c] + sQ[1][c] + sQ[2][c] + sQ[3][c];
    atomicAdd(((double*)(ws + WS_QSUM)) + c, (double)q4);
  }
}

// ---------------- D4: inline finalize + MFMA conv (8 rows/block), output ----------------
// Finalize prologue = R7-verified; conv core = R6-verified.
__global__ __launch_bounds__(256) void k_conv_out(const char* __restrict__ ws,
                                                  const float* __restrict__ gamma,
                                                  const float* __restrict__ beta,
                                                  float* __restrict__ out) {
  __shared__ int4 sXs[10 * 226];
  __shared__ float sAB[32];                          // A[16], B[16]
  const int4* __restrict__ xq = (const int4*)(ws + WS_XQ);
  const int4* __restrict__ wq4 = (const int4*)(ws + WS_WQ);
  const float* hdr_f = (const float*)ws;

  const int tid = threadIdx.x;
  const int b = blockIdx.x;
  const int n = b / NRG8, rg = b - n * NRG8;
  const int r0 = rg * 8;

  stage_strip10(xq, sXs, n, r0, tid);

  // ---- finalize (R7-verified double formula; 32 scalars, all blocks identical) ----
  if (tid < 16) {
    unsigned long long us = ((const unsigned long long*)(ws + WS_SSUM))[tid];
    double S = (double)(long long)us;                // exact integer sum
    double Q = ((const double*)(ws + WS_QSUM))[tid];
    float sf = hdr_f[2] * hdr_f[1];                  // sx * sw (f32, verified)
    double s = (double)sf;
    const double M = (double)NPIX;
    double mean = s * S / M;
    double ey2 = s * s * Q / M;
    double var = ey2 - mean * mean;                  // biased var, matches jnp.var
    double inv = (double)gamma[tid] / sqrt(var + 1e-5);
    sAB[tid] = (float)(s * inv);                     // A: applied to raw int acc
    sAB[16 + tid] = (float)((double)beta[tid] - mean * inv);  // B
  }

  const int lane = tid & 63, wid = tid >> 6;
  const int ccol = lane & 15, chunk = lane >> 4;
  v4i bfrag[3];
  int abase[3];
  conv_lane_setup(wq4, ccol, chunk, bfrag, abase);
  __syncthreads();

  const float Af = sAB[ccol];                        // BN scale for this cout
  const float Bf = sAB[16 + ccol];                   // BN shift

  float* oplane = out + ((size_t)n * 16 + ccol) * HW2;
  for (int t = wid; t < 112; t += 4) {               // 28 tiles per wave
    int ty = t / 14, x0 = (t - ty * 14) << 4;
    int off = ty * 226 + x0;
    v4i acc = {0, 0, 0, 0};
    #pragma unroll
    for (int m3 = 0; m3 < 3; ++m3) {
      int4 av = sXs[off + abase[m3]];
      v4i a; a[0] = av.x; a[1] = av.y; a[2] = av.z; a[3] = av.w;
      acc = __builtin_amdgcn_mfma_i32_16x16x64_i8(a, bfrag[m3], acc, 0, 0, 0);
    }
    // D: px = chunk*4 + r (cols x0+chunk*4 .. +3 of output row r0+ty)
    float4 o;
    o.x = fminf(fmaxf(fmaf((float)acc[0], Af, Bf), 0.0f), 6.0f);
    o.y = fminf(fmaxf(fmaf((float)acc[1], Af, Bf), 0.0f), 6.0f);
    o.z = fminf(fmaxf(fmaf((float)acc[2], Af, Bf), 0.0f), 6.0f);
    o.w = fminf(fmaxf(fmaf((float)acc[3], Af, Bf), 0.0f), 6.0f);
    int y = r0 + ty, xb = x0 + chunk * 4;            // xb % 4 == 0: aligned
    *(float4*)&oplane[y * 224 + xb] = o;
  }
}

extern "C" void kernel_launch(void* const* d_in, const int* in_sizes, int n_in,
                              void* d_out, int out_size, void* d_ws, size_t ws_size,
                              hipStream_t stream) {
  const float* x = (const float*)d_in[0];
  const float* w = (const float*)d_in[1];
  const float* gamma = (const float*)d_in[2];
  const float* beta = (const float*)d_in[3];
  float* out = (float*)d_out;
  char* ws = (char*)d_ws;

  k_absmax_wq<<<ABS_GRID, 256, 0, stream>>>(x, w, ws);
  k_quant_x<<<1568, 256, 0, stream>>>(x, ws);
  k_conv_stats<<<NBLK_CONV, 256, 0, stream>>>(ws, ws);
  k_conv_out<<<NBLK_CONV, 256, 0, stream>>>(ws, gamma, beta, out);
}